// Round 8
// baseline (123.966 us; speedup 1.0000x reference)
//
#include <hip/hip_runtime.h>
#include <cmath>

// SSIM stability loss: 1 - mean(SSIM(x,y)), 11x11 Gaussian (sigma=1.5), zero SAME
// padding, fp32, 32 x 1 x 512 x 512.
//
// R22: per-thread MLP test. All prior variants give each wave ONE dependency
// chain (ds_read row -> H-conv -> next row); busy% of the binding pipe is
// pinned at 40-44% across every TLP/barrier/schedule variant (R15-R21), and
// per-wave stall ~= the LDS round-trip that 2 barrier-correlated waves/SIMD
// can't hide. R22 gives each thread TWO independent chains: one block
// processes the same 256-col strip / 64-row band of TWO images (z, z+16).
// Per row-step: 12 ds_reads feed two independent H/V-conv chains.
// Geometry = R19's proven best: 256 thr, BROWS=64 (halo 1.156), 11-row
// chunks, single-buffer + 2 barriers/chunk. Grid (2,8,16)=256 blocks = 1/CU
// x 8 waves/CU (same waves as R19). LDS 2x23.9=47.9KB. Work identical/px.
//
// Channels: sum/diff (R19): u=(x+y)/sqrt2, v=(x-y)/sqrt2 + squares; exact
// 11 taps via parity-folded 12-tap weight vector (1-col/thread layout).
// Cycle-model note (corrected this round): v_pk_*_f32 issues in 4 cyc
// (128 FMA-lanes/CU); measured VALU-busy 17.5-18.7us matches FLOP count.
// Predict: if MLP theory right dur 42.6 -> 32-37us, VALUBusy ~55-65%;
// if neutral ~43-46 -> decomposition at structural limit.
// Tripwire: VGPR ~190-220; WRITE_SIZE must stay ~32B (no spills).

#define IMG   512
#define BROWS 64
#define NHROW (BROWS + 10)   // 74 H-rows per band
#define NCHUNK 7             // ceil(74/11)
#define CHR   11             // rows per LDS chunk (== history depth)
#define LCOLS 272            // staged cols per row (covers c0-8 .. c0+263)
#define LUNITS 68            // float4 units per staged row
#define NUNITS (CHR * LUNITS)   // 748
#define NBLOCKS 256
#define NPIX  8388608.0
#define RSQRT2 0.70710678118654752f

typedef float v2f __attribute__((ext_vector_type(2)));
typedef float v4f __attribute__((ext_vector_type(4)));

struct GaussW { float w[11]; };
struct HR { v2f L, Q; };

__global__ __launch_bounds__(256)
void ssim_stream_kernel(const float* __restrict__ x, const float* __restrict__ y,
                        double* __restrict__ acc_ws, unsigned long long* __restrict__ ctr,
                        float* __restrict__ out, GaussW gw) {
    // tile4[band][s][u] = LDS cols (2u, 2u+1) packed as (u0, v0, u1, v1)
    __shared__ v4f tile4[2][CHR][LCOLS / 2];   // 2 * 11 * 136 * 16 = 47872 B
    __shared__ float wavesum[4];

    const int tid = threadIdx.x;
    const int c0 = blockIdx.x * 256;
    const int r0 = blockIdx.y * BROWS;
    const size_t off0 = (size_t)blockIdx.z * (IMG * IMG);
    const size_t off1 = (size_t)(blockIdx.z + 16) * (IMG * IMG);
    const float* __restrict__ xb0 = x + off0;
    const float* __restrict__ yb0 = y + off0;
    const float* __restrict__ xb1 = x + off1;
    const float* __restrict__ yb1 = y + off1;

    const int ci = tid;                 // output column; taps at LDS cols ci+3..ci+13
    const int ub = (ci + 3) >> 1;       // v4f unit of aligned window base
    const int p  = (ci + 3) & 1;        // parity: tap k sits at window pos p+k

    // 12-tap per-lane weight vector: window pos m covers LDS col 2*ub + m;
    // logical tap k = m - p, so wv2[m] = w[m-p] (0 outside [0,10]).
    v2f wv2[12];
    #pragma unroll
    for (int m = 0; m < 12; ++m) {
        float lo = (m <= 10) ? gw.w[m] : 0.f;       // p == 0
        float hi = (m >= 1) ? gw.w[m - 1] : 0.f;    // p == 1
        float wm = p ? hi : lo;
        wv2[m][0] = wm; wv2[m][1] = wm;
    }
    v2f wp[11];                          // vertical weights (parity-free)
    #pragma unroll
    for (int k = 0; k < 11; ++k) { wp[k][0] = gw.w[k]; wp[k][1] = gw.w[k]; }

    float4 sxr[2][3], syr[2][3];   // staged regs, both bands

    auto load_chunk = [&](int c) {
        #pragma unroll
        for (int bnd = 0; bnd < 2; ++bnd) {
            const float* __restrict__ xb = bnd ? xb1 : xb0;
            const float* __restrict__ yb = bnd ? yb1 : yb0;
            #pragma unroll
            for (int it = 0; it < 3; ++it) {
                int idx = tid + it * 256;
                int row = idx / LUNITS;
                int u   = idx - row * LUNITS;
                int gr = r0 - 5 + c * CHR + row;       // global image row
                int gc = c0 - 8 + u * 4;               // global col of float4
                float4 vx = make_float4(0.f, 0.f, 0.f, 0.f);
                float4 vy = vx;
                if (idx < NUNITS && (unsigned)gr < IMG && (unsigned)gc < IMG) {
                    const float* px = xb + (size_t)gr * IMG + gc;
                    const float* py = yb + (size_t)gr * IMG + gc;
                    vx = *(const float4*)px;
                    vy = *(const float4*)py;
                }
                sxr[bnd][it] = vx; syr[bnd][it] = vy;
            }
        }
    };
    // stage as u=(x+y)/sqrt2, v=(x-y)/sqrt2 (zero padding maps to zero: linear)
    auto store_chunk = [&]() {
        #pragma unroll
        for (int bnd = 0; bnd < 2; ++bnd) {
            #pragma unroll
            for (int it = 0; it < 3; ++it) {
                int idx = tid + it * 256;
                if (idx < NUNITS) {
                    int row = idx / LUNITS;
                    int u   = idx - row * LUNITS;
                    const float4 vx = sxr[bnd][it], vy = syr[bnd][it];
                    tile4[bnd][row][u * 2]     = (v4f){(vx.x + vy.x) * RSQRT2, (vx.x - vy.x) * RSQRT2,
                                                       (vx.y + vy.y) * RSQRT2, (vx.y - vy.y) * RSQRT2};
                    tile4[bnd][row][u * 2 + 1] = (v4f){(vx.z + vy.z) * RSQRT2, (vx.z - vy.z) * RSQRT2,
                                                       (vx.w + vy.w) * RSQRT2, (vx.w - vy.w) * RSQRT2};
                }
            }
        }
    };

    v2f histL0[11], histQ0[11];   // band 0 H-conv history
    v2f histL1[11], histQ1[11];   // band 1
    float lsum = 0.f;
    const float C1 = 1e-4f, C2 = 9e-4f;

    // horizontal conv: 12 parity-folded taps from a 6-unit window
    auto hconv = [&](const v4f (&w6)[6]) -> HR {
        v2f hL = (v2f){0.f, 0.f};
        v2f hQ = (v2f){0.f, 0.f};
        #pragma unroll
        for (int m = 0; m < 12; ++m) {
            v2f t = (m & 1) ? w6[m >> 1].zw : w6[m >> 1].xy;
            hL = __builtin_elementwise_fma(wv2[m], t, hL);   // v_pk_fma_f32
            v2f q = t * t;                                   // v_pk_mul_f32
            hQ = __builtin_elementwise_fma(wv2[m], q, hQ);   // v_pk_fma_f32
        }
        return (HR){hL, hQ};
    };
    // vertical conv + SSIM term; s compile-time at each call site
    auto vconv = [&](const v2f (&hL)[11], const v2f (&hQ)[11], int s) -> float {
        v2f aL = (v2f){0.f, 0.f};
        v2f aQ = (v2f){0.f, 0.f};
        #pragma unroll
        for (int j = 0; j < 11; ++j) {
            const int sl = (s + 1 + j) % 11;   // static per (s,j)
            aL = __builtin_elementwise_fma(wp[j], hL[sl], aL);
            aQ = __builtin_elementwise_fma(wp[j], hQ[sl], aQ);
        }
        float a = aL[0] * aL[0], b = aL[1] * aL[1];
        float dm = a - b;              // = 2 mx my
        float sm = a + b;              // = mx^2 + my^2
        float num = (dm + C1) * ((aQ[0] - aQ[1]) - dm + C2);  // 2sxy
        float den = (sm + C1) * ((aQ[0] + aQ[1]) - sm + C2);  // sx2+sy2
        return num * __builtin_amdgcn_rcpf(den);
    };

    load_chunk(0);
    store_chunk();
    __syncthreads();

    #pragma unroll 1
    for (int c = 0; c < NCHUNK; ++c) {      // 7 chunks x 11 rows = 77 >= 74
        if (c < NCHUNK - 1) load_chunk(c + 1);  // global loads overlap chunk-c compute

        #pragma unroll
        for (int s = 0; s < CHR; ++s) {     // H-row m = 11c + s; hist slot = s
            if (!(c == NCHUNK - 1 && s >= NHROW - (NCHUNK - 1) * CHR)) {   // m < 74
                // two independent chains: 12 reads, two H-convs
                v4f w6a[6], w6b[6];
                #pragma unroll
                for (int i = 0; i < 6; ++i) w6a[i] = tile4[0][s][ub + i];
                #pragma unroll
                for (int i = 0; i < 6; ++i) w6b[i] = tile4[1][s][ub + i];

                HR ha = hconv(w6a);
                HR hb = hconv(w6b);
                histL0[s] = ha.L; histQ0[s] = ha.Q;
                histL1[s] = hb.L; histQ1[s] = hb.Q;

                // --- output row (11c + s - 10) completes now ---
                if (c > 0 || s == 10) {
                    lsum += vconv(histL0, histQ0, s);
                    lsum += vconv(histL1, histQ1, s);
                }
            }
        }

        __syncthreads();                    // everyone done reading tile
        if (c < NCHUNK - 1) { store_chunk(); __syncthreads(); }
    }

    // ---- reduction: wave shuffle -> LDS -> block partial -> fp64 atomic ----
    #pragma unroll
    for (int off = 32; off > 0; off >>= 1)
        lsum += __shfl_down(lsum, off, 64);
    if ((tid & 63) == 0) wavesum[tid >> 6] = lsum;
    __syncthreads();
    if (tid == 0) {
        float bs = wavesum[0] + wavesum[1] + wavesum[2] + wavesum[3];
        atomicAdd(acc_ws, (double)bs);
        __threadfence();
        unsigned long long old = atomicAdd(ctr, 1ull);
        if (old == (unsigned long long)(NBLOCKS - 1)) {
            __threadfence();
            double total = atomicAdd(acc_ws, 0.0);   // atomic RMW sees all prior adds
            out[0] = (float)(1.0 - total / NPIX);
        }
    }
}

extern "C" void kernel_launch(void* const* d_in, const int* in_sizes, int n_in,
                              void* d_out, int out_size, void* d_ws, size_t ws_size,
                              hipStream_t stream) {
    const float* x = (const float*)d_in[0];   // heatmap_clean
    const float* y = (const float*)d_in[1];   // heatmap_adv
    float* out = (float*)d_out;
    double* acc = (double*)d_ws;
    unsigned long long* ctr = (unsigned long long*)((char*)d_ws + 8);

    // zero the 16B of accumulator+counter state (capture-safe async memset)
    hipMemsetAsync(d_ws, 0, 16, stream);

    GaussW gw;
    double g[11], s = 0.0;
    for (int i = 0; i < 11; ++i) { double d = i - 5; g[i] = exp(-(d * d) / 4.5); s += g[i]; }
    for (int i = 0; i < 11; ++i) gw.w[i] = (float)(g[i] / s);

    dim3 grid(2, IMG / BROWS, 16);   // (2, 8, 16) = 256 blocks = 1/CU, 2 image-pairs each
    ssim_stream_kernel<<<grid, 256, 0, stream>>>(x, y, acc, ctr, out, gw);
}

// Round 9
// 119.559 us; speedup vs baseline: 1.0369x; 1.0369x over previous
//
#include <hip/hip_runtime.h>
#include <cmath>

// SSIM stability loss: 1 - mean(SSIM(x,y)), 11x11 Gaussian (sigma=1.5), zero SAME
// padding, fp32, 32 x 1 x 512 x 512.
//
// R23: BARRIER-FREE per-wave tiles. Evidence chain: busy% of the binding pipe
// is ~35% at 1 blk/CU, ~44% at 2 blk/CU, and NOTHING else moves it (grid x2
// R16, modulo sched R17, block split + dbuf R18, -20% work R19, 2-col R20/21,
// dual-chain MLP R22). Hypothesis: __syncthreads re-syncs all waves every
// chunk; 8 waves/CU then burst 6 ds_read_b128 each into the single LDS pipe
// in lockstep (convoy), so SIMDs idle together and waves never reach the
// phase offsets that would let one wave's VALU cover another's LDS latency.
// R23 removes ALL main-loop barriers: each wave owns a private 64-col strip
// with its own double-buffered 11-row LDS tile (80 staged cols = 40 v4f
// units/row; 2 x 7040 B/wave; 56.3 KB/block). A wave stages global->reg->
// ds_write into buffer b^1 while reading buffer b; DS ops of one wave are
// in-order, so wave-internal waitcnt (compiler-inserted) is the only sync.
// 4 independent waves/block, 8 independent streams/CU.
//
// Inner loop = R19 (proven): sum/diff channels u=(x+y)/sqrt2, v=(x-y)/sqrt2
// + squares; 6 aligned ds_read_b128/row; parity-folded 12-tap weight vector;
// 11-deep circular register history for the vertical conv; fp64 atomic finish.
// Cost: staging redundancy 80/64 = 1.25x (FETCH +17%, memory not binding).
//
// Predict: if convoy theory right, dur 42.6 -> 27-33us, VALUBusy 55-70%;
// if neutral ~42-46 -> correlation refuted, structural plateau.
// FETCH ~50MB, LDS ~56.6KB, VGPR ~95-115, WRITE_SIZE ~32B (spill tripwire).

#define IMG   512
#define BROWS 64
#define NHROW (BROWS + 10)   // 74 H-rows per band
#define NCHUNK 7             // ceil(74/11)
#define CHR   11             // rows per LDS chunk (== history depth)
#define WQUADS 20            // float4 col-quads per staged row per wave (80 cols)
#define WUNITS 40            // v4f units per staged row per wave
#define NQ (CHR * WQUADS)    // 220 quads per chunk per wave
#define NBLOCKS 512
#define NPIX  8388608.0
#define RSQRT2 0.70710678118654752f

typedef float v2f __attribute__((ext_vector_type(2)));
typedef float v4f __attribute__((ext_vector_type(4)));

struct GaussW { float w[11]; };

__global__ __launch_bounds__(256)
void ssim_stream_kernel(const float* __restrict__ x, const float* __restrict__ y,
                        double* __restrict__ acc_ws, unsigned long long* __restrict__ ctr,
                        float* __restrict__ out, GaussW gw) {
    // per-wave private double-buffered tile: wtile[wave][buf][row][unit]
    // unit = (u0, v0, u1, v1) packing 2 image cols.  4*2*11*40*16 = 56320 B
    __shared__ v4f wtile[4][2][CHR][WUNITS];
    __shared__ float wavesum[4];

    const int tid  = threadIdx.x;
    const int w    = tid >> 6;          // wave id (owns a 64-col strip)
    const int lane = tid & 63;
    const int c0 = blockIdx.x * 256 + w * 64;   // strip base col
    const int r0 = blockIdx.y * BROWS;
    const size_t img_off = (size_t)blockIdx.z * (IMG * IMG);
    const float* __restrict__ xb = x + img_off;
    const float* __restrict__ yb = y + img_off;

    // lane's output col = c0 + lane; taps at staged cols lane+3 .. lane+13
    // (stage base is c0-8). Aligned 6 x b128 window starting at unit ub.
    const int ub = (lane + 3) >> 1;
    const int p  = (lane + 3) & 1;      // parity: tap k sits at window pos p+k

    // 12-tap per-lane weight vector: window pos m covers staged col 2*ub + m;
    // logical tap k = m - p, so wv2[m] = w[m-p] (0 outside [0,10]).
    v2f wv2[12];
    #pragma unroll
    for (int m = 0; m < 12; ++m) {
        float lo = (m <= 10) ? gw.w[m] : 0.f;       // p == 0
        float hi = (m >= 1) ? gw.w[m - 1] : 0.f;    // p == 1
        float wm = p ? hi : lo;
        wv2[m][0] = wm; wv2[m][1] = wm;
    }
    v2f wp[11];                          // vertical weights (parity-free)
    #pragma unroll
    for (int k = 0; k < 11; ++k) { wp[k][0] = gw.w[k]; wp[k][1] = gw.w[k]; }

    float4 sxr[4], syr[4];   // staged regs for next chunk (4 iters x 64 lanes >= 220)

    auto load_chunk = [&](int c) {
        #pragma unroll
        for (int it = 0; it < 4; ++it) {
            int idx = lane + it * 64;
            int row = idx / WQUADS;
            int q   = idx - row * WQUADS;
            int gr = r0 - 5 + c * CHR + row;       // global image row
            int gc = c0 - 8 + q * 4;               // global col of float4 (16B aligned)
            float4 vx = make_float4(0.f, 0.f, 0.f, 0.f);
            float4 vy = vx;
            if (idx < NQ && (unsigned)gr < IMG && (unsigned)gc < IMG) {
                const float* px = xb + (size_t)gr * IMG + gc;
                const float* py = yb + (size_t)gr * IMG + gc;
                vx = *(const float4*)px;
                vy = *(const float4*)py;
            }
            sxr[it] = vx; syr[it] = vy;
        }
    };
    // stage as u=(x+y)/sqrt2, v=(x-y)/sqrt2 (zero padding maps to zero: linear)
    auto store_chunk = [&](int b) {
        #pragma unroll
        for (int it = 0; it < 4; ++it) {
            int idx = lane + it * 64;
            if (idx < NQ) {
                int row = idx / WQUADS;
                int q   = idx - row * WQUADS;
                const float4 vx = sxr[it], vy = syr[it];
                wtile[w][b][row][q * 2]     = (v4f){(vx.x + vy.x) * RSQRT2, (vx.x - vy.x) * RSQRT2,
                                                    (vx.y + vy.y) * RSQRT2, (vx.y - vy.y) * RSQRT2};
                wtile[w][b][row][q * 2 + 1] = (v4f){(vx.z + vy.z) * RSQRT2, (vx.z - vy.z) * RSQRT2,
                                                    (vx.w + vy.w) * RSQRT2, (vx.w - vy.w) * RSQRT2};
            }
        }
    };

    v2f histL[11];     // (hu, hv)     -- linear channel H-conv results
    v2f histQ[11];     // (huu, hvv)   -- quadratic channel H-conv results
    float lsum = 0.f;
    const float C1 = 1e-4f, C2 = 9e-4f;

    load_chunk(0);
    store_chunk(0);
    // no barrier: DS pipe is in-order within a wave; compiler inserts the
    // lgkmcnt needed before the first dependent ds_read result use.

    #pragma unroll 1
    for (int c = 0; c < NCHUNK; ++c) {      // 7 chunks x 11 rows = 77 >= 74
        const int b = c & 1;
        if (c < NCHUNK - 1) load_chunk(c + 1);  // global loads overlap chunk-c compute

        #pragma unroll
        for (int s = 0; s < CHR; ++s) {     // H-row m = 11c + s; hist slot = s
            if (!(c == NCHUNK - 1 && s >= NHROW - (NCHUNK - 1) * CHR)) {   // m < 74
                v4f w6[6];
                #pragma unroll
                for (int i = 0; i < 6; ++i) w6[i] = wtile[w][b][s][ub + i];

                // --- horizontal conv: 12 taps, 3 packed ops each ---
                v2f hL = (v2f){0.f, 0.f};
                v2f hQ = (v2f){0.f, 0.f};
                #pragma unroll
                for (int m = 0; m < 12; ++m) {
                    v2f t = (m & 1) ? w6[m >> 1].zw : w6[m >> 1].xy;
                    hL = __builtin_elementwise_fma(wv2[m], t, hL);   // v_pk_fma_f32
                    v2f q = t * t;                                   // v_pk_mul_f32
                    hQ = __builtin_elementwise_fma(wv2[m], q, hQ);   // v_pk_fma_f32
                }
                histL[s] = hL; histQ[s] = hQ;

                // --- output row (11c + s - 10) completes now ---
                if (c > 0 || s == 10) {
                    v2f aL = (v2f){0.f, 0.f};
                    v2f aQ = (v2f){0.f, 0.f};
                    #pragma unroll
                    for (int j = 0; j < 11; ++j) {
                        const int sl = (s + 1 + j) % 11;   // static per (s,j)
                        aL = __builtin_elementwise_fma(wp[j], histL[sl], aL);
                        aQ = __builtin_elementwise_fma(wp[j], histQ[sl], aQ);
                    }
                    // Mu=aL[0], Mv=aL[1], Qu=aQ[0], Qv=aQ[1]
                    float a = aL[0] * aL[0], bq = aL[1] * aL[1];
                    float dm = a - bq;             // = 2 mx my
                    float sm = a + bq;             // = mx^2 + my^2
                    float num = (dm + C1) * ((aQ[0] - aQ[1]) - dm + C2);  // 2sxy
                    float den = (sm + C1) * ((aQ[0] + aQ[1]) - sm + C2);  // sx2+sy2
                    lsum += num * __builtin_amdgcn_rcpf(den);
                }
            }
        }

        // write next chunk into this wave's OTHER buffer -- no barrier needed,
        // reads of buffer b above are older DS ops of the same wave (in-order).
        if (c < NCHUNK - 1) store_chunk(b ^ 1);
    }

    // ---- reduction: wave shuffle -> LDS -> block partial -> fp64 atomic ----
    #pragma unroll
    for (int off = 32; off > 0; off >>= 1)
        lsum += __shfl_down(lsum, off, 64);
    if (lane == 0) wavesum[w] = lsum;
    __syncthreads();
    if (tid == 0) {
        float bs = wavesum[0] + wavesum[1] + wavesum[2] + wavesum[3];
        atomicAdd(acc_ws, (double)bs);
        __threadfence();
        unsigned long long old = atomicAdd(ctr, 1ull);
        if (old == (unsigned long long)(NBLOCKS - 1)) {
            __threadfence();
            double total = atomicAdd(acc_ws, 0.0);   // atomic RMW sees all prior adds
            out[0] = (float)(1.0 - total / NPIX);
        }
    }
}

extern "C" void kernel_launch(void* const* d_in, const int* in_sizes, int n_in,
                              void* d_out, int out_size, void* d_ws, size_t ws_size,
                              hipStream_t stream) {
    const float* x = (const float*)d_in[0];   // heatmap_clean
    const float* y = (const float*)d_in[1];   // heatmap_adv
    float* out = (float*)d_out;
    double* acc = (double*)d_ws;
    unsigned long long* ctr = (unsigned long long*)((char*)d_ws + 8);

    // zero the 16B of accumulator+counter state (capture-safe async memset)
    hipMemsetAsync(d_ws, 0, 16, stream);

    GaussW gw;
    double g[11], s = 0.0;
    for (int i = 0; i < 11; ++i) { double d = i - 5; g[i] = exp(-(d * d) / 4.5); s += g[i]; }
    for (int i = 0; i < 11; ++i) gw.w[i] = (float)(g[i] / s);

    dim3 grid(2, IMG / BROWS, 32);   // (2, 8, 32) = 512 blocks = 2/CU, 4 indep waves each
    ssim_stream_kernel<<<grid, 256, 0, stream>>>(x, y, acc, ctr, out, gw);
}